// Round 6
// baseline (115.091 us; speedup 1.0000x reference)
//
#include <hip/hip_runtime.h>

// Legendre projection: out[n, dim*128 + deg] = P_deg(2*x[n,dim] - 1)
// 1,048,576 (n,dim) segments x 128 fp32 = 512 MiB output. Write-bound.
// R2: 109.5 us (block-barrier LDS). R4: 102.2 us (per-wave 8KB pipeline,
// 20 waves/CU). R5 (register-array half-keep via ternary selects on
// partially-uninitialized q[]): absmax 592 — undef hazard. R6: same
// occupancy plan (32 segs/wave, lane pairs compute redundantly, 4 KB/wave
// -> 16 KB/block -> 8 blocks/CU = 32 waves/CU) but the half-keep is an
// exec-predicated direct LDS write — no register array, no selects.
// Drain identical in structure to proven R4: per wave-instr 8 aligned full
// 128B lines, nontemporal.

#define DEG1 128

typedef float f32x4 __attribute__((ext_vector_type(4)));

__global__ __launch_bounds__(256, 8) void LegendreProjection_48644799594943_kernel(
    const float* __restrict__ x, float* __restrict__ out) {
    // Per wave: 32 segs x 8 f32x4 (one 32-degree chunk) = 4 KB.
    // Layout: flat idx = 8*seg + (w ^ (seg&7)), w = float4 index in chunk.
    __shared__ f32x4 lds[4][256];

    const int tid  = threadIdx.x;
    const int wave = tid >> 6;
    const int lane = tid & 63;
    const int seg0 = (blockIdx.x * 4 + wave) * 32;  // wave's 32 segments
    const int sl   = lane >> 1;                     // local segment
    const int h    = lane & 1;                      // which half of each chunk I write

    const float xs = 2.0f * x[seg0 + sl] - 1.0f;

    f32x4* my = lds[wave];
    f32x4* outv = reinterpret_cast<f32x4*>(out);

    float pm = 1.0f;  // P_{deg-1}
    float pc = xs;    // P_deg

#pragma unroll
    for (int c = 0; c < 4; ++c) {
        // --- compute 32 degrees (full recurrence in every lane);
        //     predicated direct LDS write of my half of the chunk ---
#pragma unroll
        for (int v8 = 0; v8 < 8; ++v8) {
            f32x4 t;
#pragma unroll
            for (int j = 0; j < 4; ++j) {
                const int deg = c * 32 + v8 * 4 + j;
                float val;
                if (deg == 0) {
                    val = 1.0f;
                } else if (deg == 1) {
                    val = xs;
                } else {
                    // P_{n+1} = ((2n+1) x P_n - n P_{n-1}) / (n+1), n = deg-1
                    const float nf = (float)(deg - 1);
                    val = ((2.0f * nf + 1.0f) * xs * pc - nf * pm) * (1.0f / (nf + 1.0f));
                    pm = pc;
                    pc = val;
                }
                t[j] = val;
            }
            if ((v8 >> 2) == h) {
                my[8 * sl + (v8 ^ (sl & 7))] = t;  // lane 2s: w 0..3, lane 2s+1: w 4..7
            }
        }

        // --- drain: 4 wave-instrs, each = 8 aligned full 128B lines ---
#pragma unroll
        for (int k = 0; k < 4; ++k) {
            const int g = lane >> 3;      // seg group within this k
            const int l = lane & 7;       // float4 (w) within chunk
            const int s = k * 8 + g;      // local segment
            const f32x4 d = my[8 * s + (l ^ g)];  // s&7 == g
            __builtin_nontemporal_store(
                d, &outv[(size_t)(seg0 + s) * (DEG1 / 4) + c * 8 + l]);
        }
    }
}

extern "C" void kernel_launch(void* const* d_in, const int* in_sizes, int n_in,
                              void* d_out, int out_size, void* d_ws, size_t ws_size,
                              hipStream_t stream) {
    const float* x = (const float*)d_in[0];
    float* out = (float*)d_out;
    const int total = in_sizes[0];   // 1,048,576 segments
    const int grid = total / 128;    // 128 segments per block (4 waves x 32)
    LegendreProjection_48644799594943_kernel<<<grid, 256, 0, stream>>>(x, out);
}

// Round 7
// 105.533 us; speedup vs baseline: 1.0906x; 1.0906x over previous
//
#include <hip/hip_runtime.h>

// Legendre projection: out[n, dim*128 + deg] = P_deg(2*x[n,dim] - 1)
// 1,048,576 (n,dim) segments x 128 fp32 = 512 MiB output. Write-bound.
// R2 (block-barrier LDS): 109.5 us. R4 (per-wave pipeline + nontemporal):
// 102.2 us (~5.3 TB/s). R6 (32 waves/CU via redundant compute): 115.1 us
// — occupancy theory falsified; stores need issue rate, not latency hiding.
// R7: exact R4 structure, nontemporal hint REMOVED (single-variable A/B).
// Harness memset (plain streaming stores) hits 6.75 TB/s; nt cache policy
// is the last structural difference on the store path.

#define DEG1 128

typedef float f32x4 __attribute__((ext_vector_type(4)));

__global__ __launch_bounds__(256) void LegendreProjection_48644799594943_kernel(
    const float* __restrict__ x, float* __restrict__ out) {
    // [wave][seg][slot], slot = vec ^ (seg&7). 4 * 64 * 8 * 16B = 32 KB.
    __shared__ f32x4 lds[4][64][8];

    const int tid  = threadIdx.x;
    const int wave = tid >> 6;
    const int lane = tid & 63;
    const int seg0 = (blockIdx.x * 4 + wave) * 64;  // this wave's 64 segments

    const float xs = 2.0f * x[seg0 + lane] - 1.0f;

    f32x4 (*my)[8] = lds[wave];
    f32x4* outv = reinterpret_cast<f32x4*>(out);

    float pm = 1.0f;  // P_{deg-1}
    float pc = xs;    // P_deg

#pragma unroll
    for (int c = 0; c < 4; ++c) {
        // --- compute 32 degrees for my segment, write swizzled to LDS ---
#pragma unroll
        for (int v = 0; v < 8; ++v) {
            f32x4 q;
#pragma unroll
            for (int j = 0; j < 4; ++j) {
                const int deg = c * 32 + v * 4 + j;
                float val;
                if (deg == 0) {
                    val = 1.0f;
                } else if (deg == 1) {
                    val = xs;
                } else {
                    // P_{n+1} = ((2n+1) x P_n - n P_{n-1}) / (n+1), n = deg-1
                    const float nf = (float)(deg - 1);
                    val = ((2.0f * nf + 1.0f) * xs * pc - nf * pm) * (1.0f / (nf + 1.0f));
                    pm = pc;
                    pc = val;
                }
                q[j] = val;
            }
            my[lane][v ^ (lane & 7)] = q;  // aligned 8-lane runs -> 8 bank groups
        }

        // --- transposed drain: 8 wave-instrs, each = 8 aligned full 128B lines ---
#pragma unroll
        for (int k = 0; k < 8; ++k) {
            const int s = k * 8 + (lane >> 3);  // local segment
            const int v = lane & 7;             // float4 index within chunk
            const f32x4 q = my[s][v ^ (s & 7)];
            outv[(size_t)(seg0 + s) * (DEG1 / 4) + c * 8 + v] = q;  // plain store
        }
    }
}

extern "C" void kernel_launch(void* const* d_in, const int* in_sizes, int n_in,
                              void* d_out, int out_size, void* d_ws, size_t ws_size,
                              hipStream_t stream) {
    const float* x = (const float*)d_in[0];
    float* out = (float*)d_out;
    const int total = in_sizes[0];   // 1,048,576 segments
    const int grid = total / 256;    // 256 segments per block (4 waves x 64)
    LegendreProjection_48644799594943_kernel<<<grid, 256, 0, stream>>>(x, out);
}

// Round 8
// 104.355 us; speedup vs baseline: 1.1029x; 1.0113x over previous
//
#include <hip/hip_runtime.h>

// Legendre projection: out[n, dim*128 + deg] = P_deg(2*x[n,dim] - 1)
// 1,048,576 (n,dim) segments x 128 fp32 = 512 MiB output. Write-bound.
// R4 (per-wave chunked pipeline + nt stores): 102.2 us (~5.3 TB/s) — best.
// R6 (32 waves/CU): 115 us — occupancy theory dead. R7 (plain stores):
// 105.5 us — nt helps, keep it.
// R8: store-stream CONTIGUITY test. R4's drain scatters 128B lines at
// 512B stride (poor DRAM page locality); memset (6.7 TB/s) walks
// contiguous. Here each wave stages ALL 128 degrees of its 64 segments
// (33-padded rows, conflict-free LDS both sides), then drains 32 KB as
// 32 nt-store instrs, each 1 KB fully contiguous — memset-identical
// pattern. LDS 33 KB/wave -> 4 waves/CU (enough: stores are
// fire-and-forget, vmcnt queue throttles to HBM rate).

#define DEG1 128

typedef float f32x4 __attribute__((ext_vector_type(4)));

__global__ __launch_bounds__(64) void LegendreProjection_48644799594943_kernel(
    const float* __restrict__ x, float* __restrict__ out) {
    // 64 segments x 33 f32x4 rows (32 data + 1 pad) = 33792 B.
    // Write: lane l, word w -> idx l*33+w: dword-bank 4(l+w)%32, each 8-lane
    // b128 phase covers all 32 banks once -> conflict-free minimum.
    // Read: idx s*33+w, w=lane&31 consecutive -> conflict-free minimum.
    __shared__ f32x4 lds[64 * 33];

    const int lane = threadIdx.x;          // 0..63, one segment per lane
    const int seg0 = blockIdx.x * 64;      // this wave's 64 segments

    const float xs = 2.0f * x[seg0 + lane] - 1.0f;

    // --- compute all 128 degrees, stage in LDS ---
    float pm = 1.0f;  // P_{deg-1}
    float pc = xs;    // P_deg
#pragma unroll
    for (int w = 0; w < 32; ++w) {
        f32x4 q;
#pragma unroll
        for (int j = 0; j < 4; ++j) {
            const int deg = w * 4 + j;
            float val;
            if (deg == 0) {
                val = 1.0f;
            } else if (deg == 1) {
                val = xs;
            } else {
                // P_{n+1} = ((2n+1) x P_n - n P_{n-1}) / (n+1), n = deg-1
                const float nf = (float)(deg - 1);
                val = ((2.0f * nf + 1.0f) * xs * pc - nf * pm) * (1.0f / (nf + 1.0f));
                pm = pc;
                pc = val;
            }
            q[j] = val;
        }
        lds[lane * 33 + w] = q;
    }

    // --- drain: 32 nt-store instrs, each 1 KB fully contiguous (2 segments),
    //     walking the wave's 32 KB output linearly (memset-identical) ---
    f32x4* outv = reinterpret_cast<f32x4*>(out) + (size_t)seg0 * (DEG1 / 4);
#pragma unroll
    for (int k = 0; k < 32; ++k) {
        const int s = 2 * k + (lane >> 5);   // local segment
        const int w = lane & 31;             // f32x4 word within segment
        const f32x4 d = lds[s * 33 + w];
        __builtin_nontemporal_store(d, &outv[k * 64 + lane]);
    }
}

extern "C" void kernel_launch(void* const* d_in, const int* in_sizes, int n_in,
                              void* d_out, int out_size, void* d_ws, size_t ws_size,
                              hipStream_t stream) {
    const float* x = (const float*)d_in[0];
    float* out = (float*)d_out;
    const int total = in_sizes[0];   // 1,048,576 segments
    const int grid = total / 64;     // 64 segments per 1-wave block
    LegendreProjection_48644799594943_kernel<<<grid, 64, 0, stream>>>(x, out);
}